// Round 9
// baseline (1448.881 us; speedup 1.0000x reference)
//
#include <hip/hip_runtime.h>
#include <stdint.h>
#include <limits.h>

// ---------- exact-rounding helpers (block FMA contraction; match numpy op order) ----------
__device__ inline float mul_rn(float a, float b){ float r; asm("v_mul_f32 %0, %1, %2" : "=v"(r) : "v"(a), "v"(b)); return r; }
__device__ inline float add_rn(float a, float b){ float r; asm("v_add_f32 %0, %1, %2" : "=v"(r) : "v"(a), "v"(b)); return r; }
__device__ inline float sub_rn(float a, float b){ float r; asm("v_sub_f32 %0, %1, %2" : "=v"(r) : "v"(a), "v"(b)); return r; }

typedef uint16_t u16x8 __attribute__((ext_vector_type(8)));

__device__ inline float bf2f(uint16_t u){ return __uint_as_float(((uint32_t)u) << 16); }
__device__ inline uint16_t f2bf(float f){
    uint32_t u = __float_as_uint(f);
    u += 0x7fffu + ((u >> 16) & 1u);   // RNE
    return (uint16_t)(u >> 16);
}
// monotonic uint key for float (total order): k(f) increasing in f
__device__ inline unsigned fkey(float f){
    unsigned u = __float_as_uint(f);
    return (u & 0x80000000u) ? ~u : (u | 0x80000000u);
}
__device__ inline float funkey(unsigned k){
    unsigned u = (k & 0x80000000u) ? (k ^ 0x80000000u) : ~k;
    return __uint_as_float(u);
}

// full-wave u32 max via DPP using the BUILTIN (compiler inserts the mandatory
// VALU->DPP hazard wait-states). Result valid in lane 63.
__device__ inline unsigned dpp_umax_wave(unsigned v){
    unsigned t;
    t = (unsigned)__builtin_amdgcn_update_dpp((int)v, (int)v, 0x111, 0xf, 0xf, false); v = v > t ? v : t; // row_shr:1
    t = (unsigned)__builtin_amdgcn_update_dpp((int)v, (int)v, 0x112, 0xf, 0xf, false); v = v > t ? v : t; // row_shr:2
    t = (unsigned)__builtin_amdgcn_update_dpp((int)v, (int)v, 0x114, 0xf, 0xf, false); v = v > t ? v : t; // row_shr:4
    t = (unsigned)__builtin_amdgcn_update_dpp((int)v, (int)v, 0x118, 0xf, 0xf, false); v = v > t ? v : t; // row_shr:8
    t = (unsigned)__builtin_amdgcn_update_dpp((int)v, (int)v, 0x142, 0xf, 0xf, false); v = v > t ? v : t; // row_bcast:15
    t = (unsigned)__builtin_amdgcn_update_dpp((int)v, (int)v, 0x143, 0xf, 0xf, false); v = v > t ? v : t; // row_bcast:31
    return v;
}

#define NPTS   8192
#define NBATCH 16
#define NPOINT 1024
#define NSAMP  32
#define LCOLS  32768          // NPOINT*NSAMP
#define NTOT   524288.0f      // 16*32768
#define NBUCK  32

// ---------- workspace layout (bytes) ----------
#define OFF_FPS   0u               // 16*1024*4 = 65536
#define OFF_GIDX  65536u           // 16*1024*32*4 = 2097152
#define OFF_SSC   2162688u         // 3 layers * 32 buckets * 256 f32 = 98304
#define OFF_PAR   2260992u         // 2 layers * 256 f32 = 2048
#define OFF_MM    2263040u         // mmax 2048 u32 ; mmin 2048 u32 = 16384
#define OFF_WT    2279424u         // 66304
#define OFF_T0    4194304u         // 67108864
#define OFF_T1    71303168u        // 67108864
#define OFF_PTST  138412032u       // 16777216 (end 155189248)

// ---------- 1) FUSED (256 thr/block): fps (0..15) + pts transpose (16..2063) + prep (2064..2095) ----------
__global__ __launch_bounds__(256) void fps_fused_kernel(const float* __restrict__ xyz,
        int* __restrict__ fps_idx, float* __restrict__ out_xyz,
        const float* __restrict__ pts, uint16_t* __restrict__ ptsT,
        const float* __restrict__ w0, const float* __restrict__ w1, const float* __restrict__ w2,
        float* __restrict__ wt0, float* __restrict__ wt1, float* __restrict__ wt2){
#pragma clang fp contract(off)
    __shared__ __align__(16) float smem[33808];   // sxyz4 32768 + wslots 16 + sidx 1024
    const int bid = blockIdx.x, tid = threadIdx.x;

    if (bid >= 2064){                      // ---- prep path: wt[c][o] transposes ----
        int t = (bid - 2064) * 256 + tid;  // 0..8191
        if (t < 64*67){ int o = t / 67, c = t % 67; wt0[c*64 + o] = w0[t]; }
        if (t < 64*64){ int o = t >> 6, c = t & 63; wt1[c*64 + o] = w1[t]; }
        if (t < 128*64){ int o = t >> 6, c = t & 63; wt2[c*128 + o] = w2[t]; }
        return;
    }
    if (bid >= 16){                        // ---- transpose path: (B,64,N)f32 -> (B,N,64)bf16 ----
        float (*tile)[65] = (float(*)[65])smem;
        const int tb = bid - 16;
        const int bt = tb >> 7, n0 = (tb & 127) << 6;
        const int tn = tid & 63, tg = tid >> 6;
        const float* src = pts + (size_t)bt * 64 * NPTS + n0;
#pragma unroll
        for (int i = 0; i < 16; i++){ int c = tg*16 + i; tile[c][tn] = src[(size_t)c * NPTS + tn]; }
        __syncthreads();
        uint16_t* dst = ptsT + ((size_t)bt * NPTS + n0) * 64;
#pragma unroll
        for (int i = 0; i < 16; i++){ int n = tg*16 + i; dst[(size_t)n * 64 + tn] = f2bf(tile[tn][n]); }
        return;
    }

    // ---- fps path: 256 threads (1 wave/SIMD), 32 points/thread, plain-C update ----
    float* sxyz = smem;                                                 // [8192*4] xyz pad
    float4* sxyz4 = (float4*)smem;
    unsigned long long* wslots = (unsigned long long*)(smem + 32768);   // [2*4]
    int* sidx = (int*)(smem + 32784);                                   // [1024]
    const int b = bid;
    const float* px = xyz + (size_t)b * 3 * NPTS;
    for (int i = tid; i < NPTS; i += 256)
        sxyz4[i] = float4{px[i], px[NPTS + i], px[2*NPTS + i], 0.f};
    __syncthreads();

    const int p0 = tid << 5;
    const float4* rp = sxyz4 + p0;
    float X[32], Y[32], Z[32], M[32];
#pragma unroll
    for (int j = 0; j < 32; j++){ float4 q = rp[j]; X[j] = q.x; Y[j] = q.y; Z[j] = q.z; M[j] = 1e10f; }
    const unsigned base = ~(unsigned)p0;          // ~(p0+j) == base - j

    int cur = 0;
    float cx = sxyz[0], cy = sxyz[1], cz = sxyz[2];
    for (int t = 0; t < NPOINT; t++){
        if (tid == 0) sidx[t] = cur;               // record this iteration's centroid
#pragma unroll
        for (int j = 0; j < 32; j++){
            float dx = X[j] - cx, dy = Y[j] - cy, dz = Z[j] - cz;
            float d  = dx*dx + dy*dy + dz*dz;      // contract(off): mul,add each RNE
            M[j] = fminf(M[j], d);
        }
        // thread-local max over 32 values (fmax is exact: tree shape irrelevant)
        float t0_ = fmaxf(fmaxf(fmaxf(M[0],M[1]),fmaxf(M[2],M[3])), fmaxf(fmaxf(M[4],M[5]),fmaxf(M[6],M[7])));
        float t1_ = fmaxf(fmaxf(fmaxf(M[8],M[9]),fmaxf(M[10],M[11])), fmaxf(fmaxf(M[12],M[13]),fmaxf(M[14],M[15])));
        float t2_ = fmaxf(fmaxf(fmaxf(M[16],M[17]),fmaxf(M[18],M[19])), fmaxf(fmaxf(M[20],M[21]),fmaxf(M[22],M[23])));
        float t3_ = fmaxf(fmaxf(fmaxf(M[24],M[25]),fmaxf(M[26],M[27])), fmaxf(fmaxf(M[28],M[29]),fmaxf(M[30],M[31])));
        const float mt = fmaxf(fmaxf(t0_, t1_), fmaxf(t2_, t3_));
        // smallest owned position with M==mt (descending scan -> smallest j wins)
        unsigned jpos = 0;
#pragma unroll
        for (int j = 31; j >= 0; j--) if (M[j] == mt) jpos = j;
        const unsigned lo = base - jpos;           // == ~(p0 + jpos)
        const unsigned mtu = __float_as_uint(mt);  // d>=0 -> uint order == float order
        unsigned vm = dpp_umax_wave(mtu);
        const unsigned wvu = __builtin_amdgcn_readlane(vm, 63);
        unsigned long long cand = __ballot(mtu == wvu);
        const int fl = __ffsll((long long)cand) - 1;        // lowest lane = smallest p
        const unsigned wlo = __builtin_amdgcn_readlane(lo, fl);
        if ((tid & 63) == 0)
            wslots[(t & 1) * 4 + (tid >> 6)] = (((unsigned long long)wvu) << 32) | wlo;
        __syncthreads();                            // the ONLY barrier per iter
        const ulonglong2* sp = (const ulonglong2*)(wslots + (t & 1) * 4);
        ulonglong2 ka = sp[0], kb = sp[1];          // 2 uniform b128 reads (broadcast)
        unsigned long long ma = (ka.y > ka.x) ? ka.y : ka.x;
        unsigned long long mb = (kb.y > kb.x) ? kb.y : kb.x;
        unsigned long long win = (mb > ma) ? mb : ma;
        cur = (int)(~((unsigned)win));
        const float4 cc = sxyz4[cur];               // single uniform b128 read
        cx = cc.x; cy = cc.y; cz = cc.z;
    }
    __syncthreads();
    // output phase: 4 per thread
#pragma unroll
    for (int q = 0; q < 4; q++){
        const int i = (q << 8) + tid;
        const int idx = sidx[i];
        fps_idx[b * NPOINT + i] = idx;
        const float4 c4 = sxyz4[idx];
        float* oxp = out_xyz + b * 3 * NPOINT;
        oxp[i]            = c4.x;
        oxp[NPOINT + i]   = c4.y;
        oxp[2*NPOINT + i] = c4.z;
    }
}

// ---------- 2) ball query: one wave per (b,s) ----------
__global__ __launch_bounds__(256) void ballquery_kernel(const float* __restrict__ xyz,
                                                        const int* __restrict__ fps_idx, int* __restrict__ gidx){
    const int w = (blockIdx.x << 2) + (threadIdx.x >> 6);
    const int lane = threadIdx.x & 63;
    const int b = w >> 10, s = w & 1023;
    const float* px = xyz + (size_t)b * 3 * NPTS;
    const int ci = fps_idx[b * NPOINT + s];
    const float cx = px[ci], cy = px[NPTS+ci], cz = px[2*NPTS+ci];
    int* gout = gidx + (size_t)b * LCOLS + s * NSAMP;
    int have = 0, first_p = 0; bool got = false;
    for (int c0 = 0; c0 < NPTS; c0 += 64){
        int p = c0 + lane;
        float dx = sub_rn(px[p], cx), dy = sub_rn(px[NPTS+p], cy), dz = sub_rn(px[2*NPTS+p], cz);
        float d2 = add_rn(add_rn(mul_rn(dx,dx), mul_rn(dy,dy)), mul_rn(dz,dz));
        bool in = (d2 <= 0.01f);
        unsigned long long m = __ballot(in);
        if (m && !got){ first_p = c0 + __ffsll(m) - 1; got = true; }
        if (in){
            int pos = have + __popcll(m & ((1ull << lane) - 1ull));
            if (pos < NSAMP) gout[pos] = p;
        }
        have += __popcll(m);
        if (have >= NSAMP) break;
    }
    for (int pos = have + lane; pos < NSAMP; pos += 64) gout[pos] = first_p;
}

// ---------- 3) fused conv+BN-stats kernel ----------
template<int CIN, int COUT, bool ACT, bool GATHER, bool WRITE, bool MAXMIN>
__global__ __launch_bounds__(256) void mm_kernel(const uint16_t* __restrict__ xin,
        const float* __restrict__ xyz, const float* __restrict__ nx,
        const uint16_t* __restrict__ ptsT, const int* __restrict__ gidx,
        const float* __restrict__ wt, const float* __restrict__ bias, const float* __restrict__ ac,
        uint16_t* __restrict__ xout, float* __restrict__ ssc,
        unsigned* __restrict__ mmax, unsigned* __restrict__ mmin){
    __shared__ __align__(16) float sw[CIN * COUT];
    __shared__ float sb[COUT];
    __shared__ float sa[ACT ? 2*CIN : 1];
    __shared__ __align__(16) float sred[16 * 260];
    const int tid = threadIdx.x;
    for (int i = tid; i < CIN * COUT; i += 256) sw[i] = wt[i];
    if (tid < COUT) sb[tid] = bias[tid];
    if constexpr (ACT){ if (tid < CIN){ sa[tid] = ac[tid]; sa[CIN + tid] = ac[128 + tid]; } }
    __syncthreads();
    const int b = blockIdx.x >> 7;
    const int ls = ((blockIdx.x & 127) << 8) + tid;
    float f[CIN];
    if constexpr (GATHER){
        const int s = ls >> 5;
        const int g = gidx[(size_t)b * LCOLS + ls];
        const float* px = xyz + (size_t)b * 3 * NPTS;
        const float cx = nx[b*3*NPOINT + s], cy = nx[b*3*NPOINT + NPOINT + s], cz = nx[b*3*NPOINT + 2*NPOINT + s];
        f[0] = sub_rn(px[g], cx); f[1] = sub_rn(px[NPTS+g], cy); f[2] = sub_rn(px[2*NPTS+g], cz);
        const u16x8* pr = (const u16x8*)(ptsT + ((size_t)b * NPTS + (size_t)g) * 64);
#pragma unroll
        for (int jj = 0; jj < 8; jj++){
            u16x8 v = pr[jj];
#pragma unroll
            for (int e = 0; e < 8; e++) f[3 + jj*8 + e] = bf2f(v[e]);
        }
    } else {
        const uint16_t* xp = xin + (size_t)b * CIN * LCOLS + ls;
#pragma unroll
        for (int c = 0; c < CIN; c++){
            float v = bf2f(xp[(size_t)c * LCOLS]);
            if constexpr (ACT) v = fmaxf(fmaf(sa[c], v, sa[CIN + c]), 0.0f);
            f[c] = v;
        }
    }
    uint16_t* op = xout + (size_t)b * COUT * LCOLS + ls;
    float* sbck = ssc + (blockIdx.x & (NBUCK-1)) * 256;
    for (int o0 = 0; o0 < COUT; o0 += 16){
        float acc[16];
#pragma unroll
        for (int j = 0; j < 16; j++) acc[j] = sb[o0 + j];
#pragma unroll
        for (int c = 0; c < CIN; c++){
            const float4* wr = (const float4*)(sw + c * COUT + o0);  // uniform -> LDS broadcast
            float4 w0_ = wr[0], w1_ = wr[1], w2_ = wr[2], w3_ = wr[3];
            const float fc = f[c];
            acc[0]  = fmaf(w0_.x, fc, acc[0]);  acc[1]  = fmaf(w0_.y, fc, acc[1]);
            acc[2]  = fmaf(w0_.z, fc, acc[2]);  acc[3]  = fmaf(w0_.w, fc, acc[3]);
            acc[4]  = fmaf(w1_.x, fc, acc[4]);  acc[5]  = fmaf(w1_.y, fc, acc[5]);
            acc[6]  = fmaf(w1_.z, fc, acc[6]);  acc[7]  = fmaf(w1_.w, fc, acc[7]);
            acc[8]  = fmaf(w2_.x, fc, acc[8]);  acc[9]  = fmaf(w2_.y, fc, acc[9]);
            acc[10] = fmaf(w2_.z, fc, acc[10]); acc[11] = fmaf(w2_.w, fc, acc[11]);
            acc[12] = fmaf(w3_.x, fc, acc[12]); acc[13] = fmaf(w3_.y, fc, acc[13]);
            acc[14] = fmaf(w3_.z, fc, acc[14]); acc[15] = fmaf(w3_.w, fc, acc[15]);
        }
        if constexpr (WRITE){
#pragma unroll
            for (int j = 0; j < 16; j++) op[(size_t)(o0 + j) * LCOLS] = f2bf(acc[j]);
        }
        // ---- block-level stats reduce on f32 accs ----
        __syncthreads();                       // protect sred reuse from previous group
#pragma unroll
        for (int k = 0; k < 16; k++) sred[k * 260 + tid] = acc[k];
        __syncthreads();
        const int ch = tid >> 4, seg = tid & 15;    // 16 ch x 16 segments of 16 cols
        float s = 0.f, ss = 0.f, mx = -1e30f, mn = 1e30f;
        const float4* rp = (const float4*)(sred + ch * 260 + seg * 16);
#pragma unroll
        for (int e = 0; e < 4; e++){
            float4 v = rp[e];
            s += v.x + v.y + v.z + v.w;
            ss = fmaf(v.x, v.x, ss); ss = fmaf(v.y, v.y, ss);
            ss = fmaf(v.z, v.z, ss); ss = fmaf(v.w, v.w, ss);
            if constexpr (MAXMIN){
                mx = fmaxf(mx, fmaxf(fmaxf(v.x, v.y), fmaxf(v.z, v.w)));
                mn = fminf(mn, fminf(fminf(v.x, v.y), fminf(v.z, v.w)));
            }
        }
        // 16 segs of one ch sit in consecutive lanes of one wave
#pragma unroll
        for (int off = 1; off < 16; off <<= 1){
            s += __shfl_xor(s, off); ss += __shfl_xor(ss, off);
            if constexpr (MAXMIN){ mx = fmaxf(mx, __shfl_xor(mx, off)); mn = fminf(mn, __shfl_xor(mn, off)); }
        }
        if (seg == 0){
            atomicAdd(&sbck[o0 + ch], s);
            atomicAdd(&sbck[128 + o0 + ch], ss);
            if constexpr (MAXMIN){
                atomicMax(&mmax[b * 128 + o0 + ch], fkey(mx));
                atomicMin(&mmin[b * 128 + o0 + ch], fkey(mn));
            }
        }
    }
}

// ---------- 4) BN params from bucketed sums -> per-channel affine a,c ----------
__global__ void params_kernel(const float* __restrict__ ssc, const float* __restrict__ g,
                              const float* __restrict__ beta, float* __restrict__ ac, int C){
    int o = threadIdx.x;
    if (o < C){
        float s = 0.f, ss = 0.f;
        for (int k = 0; k < NBUCK; k++){ s += ssc[k*256 + o]; ss += ssc[k*256 + 128 + o]; }
        const float inv = 1.0f / NTOT;
        float mean = s * inv;
        float var  = ss * inv - mean * mean;
        float a = g[o] / sqrtf(var + 1e-5f);
        ac[o] = a;
        ac[128 + o] = fmaf(-mean, a, beta[o]);
    }
}

// ---------- 5) finalize: out = relu(a * (a>=0 ? max : min) + c) per (b,ch) ----------
__global__ __launch_bounds__(64) void final_kernel(const float* __restrict__ ssc, const float* __restrict__ g2,
                                                   const float* __restrict__ be2, const unsigned* __restrict__ mmax,
                                                   const unsigned* __restrict__ mmin, float* __restrict__ out){
    const int t = blockIdx.x * 64 + threadIdx.x;   // 0..2047 : b*128+o
    const int o = t & 127;
    float s = 0.f, ss = 0.f;
    for (int k = 0; k < NBUCK; k++){ s += ssc[k*256 + o]; ss += ssc[k*256 + 128 + o]; }
    const float inv = 1.0f / NTOT;
    float mean = s * inv;
    float var  = ss * inv - mean * mean;
    float a = g2[o] / sqrtf(var + 1e-5f);
    float c = fmaf(-mean, a, be2[o]);
    unsigned k = (a >= 0.f) ? mmax[t] : mmin[t];   // relu(a*x+c) monotone in x, direction sign(a)
    float x = funkey(k);
    out[49152 + t] = fmaxf(fmaf(a, x, c), 0.0f);
}

extern "C" void kernel_launch(void* const* d_in, const int* in_sizes, int n_in,
                              void* d_out, int out_size, void* d_ws, size_t ws_size,
                              hipStream_t stream){
    const float* xyz = (const float*)d_in[0];
    const float* pts = (const float*)d_in[1];
    const float* w0  = (const float*)d_in[2];  const float* b0  = (const float*)d_in[3];
    const float* g0  = (const float*)d_in[4];  const float* be0 = (const float*)d_in[5];
    const float* w1  = (const float*)d_in[6];  const float* b1  = (const float*)d_in[7];
    const float* g1  = (const float*)d_in[8];  const float* be1 = (const float*)d_in[9];
    const float* w2  = (const float*)d_in[10]; const float* b2  = (const float*)d_in[11];
    const float* g2  = (const float*)d_in[12]; const float* be2 = (const float*)d_in[13];
    float* out = (float*)d_out;
    char* ws = (char*)d_ws;

    int*      fps_idx = (int*)(ws + OFF_FPS);
    int*      gidx    = (int*)(ws + OFF_GIDX);
    float*    ssc0    = (float*)(ws + OFF_SSC);            // 32*256
    float*    ssc1    = ssc0 + NBUCK*256;
    float*    ssc2    = ssc1 + NBUCK*256;
    float*    par0    = (float*)(ws + OFF_PAR);
    float*    par1    = par0 + 256;
    unsigned* mmax    = (unsigned*)(ws + OFF_MM);
    unsigned* mmin    = mmax + 2048;
    float*    wt0     = (float*)(ws + OFF_WT);
    float*    wt1     = wt0 + 67*64;
    float*    wt2     = wt1 + 64*64;
    uint16_t* t0      = (uint16_t*)(ws + OFF_T0);
    uint16_t* t1      = (uint16_t*)(ws + OFF_T1);
    uint16_t* ptsT    = (uint16_t*)(ws + OFF_PTST);

    hipMemsetAsync(ws + OFF_SSC, 0, 3 * NBUCK * 256 * 4, stream);
    hipMemsetAsync(ws + OFF_MM, 0x00, 8192, stream);          // key 0 < key(-inf)
    hipMemsetAsync(ws + OFF_MM + 8192, 0xFF, 8192, stream);   // key ~0 > key(+inf)

    fps_fused_kernel<<<2096, 256, 0, stream>>>(xyz, fps_idx, out, pts, ptsT,
                                               w0, w1, w2, wt0, wt1, wt2);
    ballquery_kernel<<<4096, 256, 0, stream>>>(xyz, fps_idx, gidx);

    mm_kernel<67, 64, false, true, true, false><<<2048, 256, 0, stream>>>(
        nullptr, xyz, out, ptsT, gidx, wt0, b0, nullptr, t0, ssc0, nullptr, nullptr);
    params_kernel<<<1, 128, 0, stream>>>(ssc0, g0, be0, par0, 64);

    mm_kernel<64, 64, true, false, true, false><<<2048, 256, 0, stream>>>(
        t0, nullptr, nullptr, nullptr, nullptr, wt1, b1, par0, t1, ssc1, nullptr, nullptr);
    params_kernel<<<1, 128, 0, stream>>>(ssc1, g1, be1, par1, 64);

    mm_kernel<64, 128, true, false, false, true><<<2048, 256, 0, stream>>>(
        t1, nullptr, nullptr, nullptr, nullptr, wt2, b2, par1, nullptr, ssc2, mmax, mmin);
    final_kernel<<<32, 64, 0, stream>>>(ssc2, g2, be2, mmax, mmin, out);
}

// Round 11
// 1419.102 us; speedup vs baseline: 1.0210x; 1.0210x over previous
//
#include <hip/hip_runtime.h>
#include <stdint.h>
#include <limits.h>

// ---------- exact-rounding helpers (block FMA contraction; match numpy op order) ----------
__device__ inline float mul_rn(float a, float b){ float r; asm("v_mul_f32 %0, %1, %2" : "=v"(r) : "v"(a), "v"(b)); return r; }
__device__ inline float add_rn(float a, float b){ float r; asm("v_add_f32 %0, %1, %2" : "=v"(r) : "v"(a), "v"(b)); return r; }
__device__ inline float sub_rn(float a, float b){ float r; asm("v_sub_f32 %0, %1, %2" : "=v"(r) : "v"(a), "v"(b)); return r; }

typedef uint16_t u16x8 __attribute__((ext_vector_type(8)));

__device__ inline float bf2f(uint16_t u){ return __uint_as_float(((uint32_t)u) << 16); }
__device__ inline uint16_t f2bf(float f){
    uint32_t u = __float_as_uint(f);
    u += 0x7fffu + ((u >> 16) & 1u);   // RNE
    return (uint16_t)(u >> 16);
}
// monotonic uint key for float (total order): k(f) increasing in f
__device__ inline unsigned fkey(float f){
    unsigned u = __float_as_uint(f);
    return (u & 0x80000000u) ? ~u : (u | 0x80000000u);
}
__device__ inline float funkey(unsigned k){
    unsigned u = (k & 0x80000000u) ? (k ^ 0x80000000u) : ~k;
    return __uint_as_float(u);
}

// full-wave u32 max via DPP builtins (compiler inserts hazard waits). Valid in lane 63.
__device__ inline unsigned dpp_umax_wave(unsigned v){
    unsigned t;
    t = (unsigned)__builtin_amdgcn_update_dpp((int)v, (int)v, 0x111, 0xf, 0xf, false); v = v > t ? v : t; // row_shr:1
    t = (unsigned)__builtin_amdgcn_update_dpp((int)v, (int)v, 0x112, 0xf, 0xf, false); v = v > t ? v : t; // row_shr:2
    t = (unsigned)__builtin_amdgcn_update_dpp((int)v, (int)v, 0x114, 0xf, 0xf, false); v = v > t ? v : t; // row_shr:4
    t = (unsigned)__builtin_amdgcn_update_dpp((int)v, (int)v, 0x118, 0xf, 0xf, false); v = v > t ? v : t; // row_shr:8
    t = (unsigned)__builtin_amdgcn_update_dpp((int)v, (int)v, 0x142, 0xf, 0xf, false); v = v > t ? v : t; // row_bcast:15
    t = (unsigned)__builtin_amdgcn_update_dpp((int)v, (int)v, 0x143, 0xf, 0xf, false); v = v > t ? v : t; // row_bcast:31
    return v;
}

#define NPTS   8192
#define NBATCH 16
#define NPOINT 1024
#define NSAMP  32
#define LCOLS  32768          // NPOINT*NSAMP
#define NTOT   524288.0f      // 16*32768
#define NBUCK  32

// ---------- workspace layout (bytes) ----------
#define OFF_FPS   0u               // 16*1024*4 = 65536
#define OFF_GIDX  65536u           // 16*1024*32*4 = 2097152
#define OFF_SSC   2162688u         // 3 layers * 32 buckets * 256 f32 = 98304
#define OFF_MM    2263040u         // mmax 2048 u32 ; mmin 2048 u32 = 16384
#define OFF_WT    2279424u         // 66304
#define OFF_T0    4194304u         // 67108864
#define OFF_T1    71303168u        // 67108864
#define OFF_PTST  138412032u       // 16777216 (end 155189248)

// ---------- 1) FUSED (512 thr/block): fps (0..15) + pts transpose (16..2063) + prep (2064..2079) ----------
__global__ __launch_bounds__(512) void fps_fused_kernel(const float* __restrict__ xyz,
        int* __restrict__ fps_idx, float* __restrict__ out_xyz,
        const float* __restrict__ pts, uint16_t* __restrict__ ptsT,
        const float* __restrict__ w0, const float* __restrict__ w1, const float* __restrict__ w2,
        float* __restrict__ wt0, float* __restrict__ wt1, float* __restrict__ wt2){
#pragma clang fp contract(off)
    __shared__ __align__(16) float smem[33824];   // sxyz4 32768 + wslots 32 + sidx 1024
    const int bid = blockIdx.x, tid = threadIdx.x;

    if (bid >= 2064){                      // ---- prep path: wt[c][o] transposes ----
        int t = (bid - 2064) * 512 + tid;  // 0..8191
        if (t < 64*67){ int o = t / 67, c = t % 67; wt0[c*64 + o] = w0[t]; }
        if (t < 64*64){ int o = t >> 6, c = t & 63; wt1[c*64 + o] = w1[t]; }
        if (t < 128*64){ int o = t >> 6, c = t & 63; wt2[c*128 + o] = w2[t]; }
        return;
    }
    if (bid >= 16){                        // ---- transpose path: (B,64,N)f32 -> (B,N,64)bf16 ----
        float (*tile)[65] = (float(*)[65])smem;
        const int tb = bid - 16;
        const int bt = tb >> 7, n0 = (tb & 127) << 6;
        const int tn = tid & 63, tg = tid >> 6;             // tg 0..7, 8 c's each
        const float* src = pts + (size_t)bt * 64 * NPTS + n0;
#pragma unroll
        for (int i = 0; i < 8; i++){ int c = tg*8 + i; tile[c][tn] = src[(size_t)c * NPTS + tn]; }
        __syncthreads();
        uint16_t* dst = ptsT + ((size_t)bt * NPTS + n0) * 64;
#pragma unroll
        for (int i = 0; i < 8; i++){ int n = tg*8 + i; dst[(size_t)n * 64 + tn] = f2bf(tile[tn][n]); }
        return;
    }

    // ---- fps path: 512 threads (2 waves/SIMD for latency overlap), 16 points/thread ----
    float* sxyz = smem;                                                 // [8192*4] xyz pad
    float4* sxyz4 = (float4*)smem;
    unsigned long long* wslots = (unsigned long long*)(smem + 32768);   // [2*8] = floats 32768..32800
    int* sidx = (int*)(smem + 32800);                                   // [1024] floats 32800..33824
    const int b = bid;
    const float* px = xyz + (size_t)b * 3 * NPTS;
    for (int i = tid; i < NPTS; i += 512)
        sxyz4[i] = float4{px[i], px[NPTS + i], px[2*NPTS + i], 0.f};
    __syncthreads();

    const int p0 = tid << 4;
    const float4* rp = sxyz4 + p0;
    float X[16], Y[16], Z[16], M[16];
#pragma unroll
    for (int j = 0; j < 16; j++){ float4 q = rp[j]; X[j] = q.x; Y[j] = q.y; Z[j] = q.z; M[j] = 1e10f; }
    const unsigned base = ~(unsigned)p0;          // ~(p0+j) == base - j

    int cur = 0;
    float cx = sxyz[0], cy = sxyz[1], cz = sxyz[2];
    for (int t = 0; t < NPOINT; t++){
        if (tid == 0) sidx[t] = cur;               // record this iteration's centroid
#pragma unroll
        for (int j = 0; j < 16; j++){
            float dx = X[j] - cx, dy = Y[j] - cy, dz = Z[j] - cz;
            float d  = dx*dx + dy*dy + dz*dz;      // contract(off): mul,add each RNE
            M[j] = fminf(M[j], d);
        }
        float t0_ = fmaxf(fmaxf(fmaxf(M[0],M[1]),fmaxf(M[2],M[3])), fmaxf(fmaxf(M[4],M[5]),fmaxf(M[6],M[7])));
        float t1_ = fmaxf(fmaxf(fmaxf(M[8],M[9]),fmaxf(M[10],M[11])), fmaxf(fmaxf(M[12],M[13]),fmaxf(M[14],M[15])));
        const float mt = fmaxf(t0_, t1_);
        // smallest owned position with M==mt (descending scan -> smallest j wins)
        unsigned jpos = 0;
#pragma unroll
        for (int j = 15; j >= 0; j--) if (M[j] == mt) jpos = j;
        const unsigned lo = base - jpos;           // == ~(p0 + jpos)
        const unsigned mtu = __float_as_uint(mt);  // d>=0 -> uint order == float order
        unsigned vm = dpp_umax_wave(mtu);
        const unsigned wvu = __builtin_amdgcn_readlane(vm, 63);
        unsigned long long cand = __ballot(mtu == wvu);
        const int fl = __ffsll((long long)cand) - 1;        // lowest lane = smallest p
        const unsigned wlo = __builtin_amdgcn_readlane(lo, fl);
        if ((tid & 63) == 0)
            wslots[(t & 1) * 8 + (tid >> 6)] = (((unsigned long long)wvu) << 32) | wlo;
        __syncthreads();                            // the ONLY barrier per iter
        const ulonglong2* sp = (const ulonglong2*)(wslots + (t & 1) * 8);
        ulonglong2 ka = sp[0], kb = sp[1], kc = sp[2], kd = sp[3];   // 4 uniform b128 reads
        unsigned long long ma = (ka.y > ka.x) ? ka.y : ka.x;
        unsigned long long mb = (kb.y > kb.x) ? kb.y : kb.x;
        unsigned long long mc = (kc.y > kc.x) ? kc.y : kc.x;
        unsigned long long md = (kd.y > kd.x) ? kd.y : kd.x;
        unsigned long long mab = (mb > ma) ? mb : ma;
        unsigned long long mcd = (md > mc) ? md : mc;
        unsigned long long win = (mcd > mab) ? mcd : mab;
        cur = (int)(~((unsigned)win));
        const float4 cc = sxyz4[cur];               // single uniform b128 read
        cx = cc.x; cy = cc.y; cz = cc.z;
    }
    __syncthreads();
    // output phase: 2 per thread
#pragma unroll
    for (int q = 0; q < 2; q++){
        const int i = (q << 9) + tid;
        const int idx = sidx[i];
        fps_idx[b * NPOINT + i] = idx;
        const float4 c4 = sxyz4[idx];
        float* oxp = out_xyz + b * 3 * NPOINT;
        oxp[i]            = c4.x;
        oxp[NPOINT + i]   = c4.y;
        oxp[2*NPOINT + i] = c4.z;
    }
}

// ---------- 2) ball query: one wave per (b,s) ----------
__global__ __launch_bounds__(256) void ballquery_kernel(const float* __restrict__ xyz,
                                                        const int* __restrict__ fps_idx, int* __restrict__ gidx){
    const int w = (blockIdx.x << 2) + (threadIdx.x >> 6);
    const int lane = threadIdx.x & 63;
    const int b = w >> 10, s = w & 1023;
    const float* px = xyz + (size_t)b * 3 * NPTS;
    const int ci = fps_idx[b * NPOINT + s];
    const float cx = px[ci], cy = px[NPTS+ci], cz = px[2*NPTS+ci];
    int* gout = gidx + (size_t)b * LCOLS + s * NSAMP;
    int have = 0, first_p = 0; bool got = false;
    for (int c0 = 0; c0 < NPTS; c0 += 64){
        int p = c0 + lane;
        float dx = sub_rn(px[p], cx), dy = sub_rn(px[NPTS+p], cy), dz = sub_rn(px[2*NPTS+p], cz);
        float d2 = add_rn(add_rn(mul_rn(dx,dx), mul_rn(dy,dy)), mul_rn(dz,dz));
        bool in = (d2 <= 0.01f);
        unsigned long long m = __ballot(in);
        if (m && !got){ first_p = c0 + __ffsll(m) - 1; got = true; }
        if (in){
            int pos = have + __popcll(m & ((1ull << lane) - 1ull));
            if (pos < NSAMP) gout[pos] = p;
        }
        have += __popcll(m);
        if (have >= NSAMP) break;
    }
    for (int pos = have + lane; pos < NSAMP; pos += 64) gout[pos] = first_p;
}

// ---------- 3) fused conv+BN-stats kernel; BN params computed per-block from prev-layer sums ----------
template<int CIN, int COUT, bool ACT, bool GATHER, bool WRITE, bool MAXMIN>
__global__ __launch_bounds__(256) void mm_kernel(const uint16_t* __restrict__ xin,
        const float* __restrict__ xyz, const float* __restrict__ nx,
        const uint16_t* __restrict__ ptsT, const int* __restrict__ gidx,
        const float* __restrict__ wt, const float* __restrict__ bias,
        const float* __restrict__ pssc, const float* __restrict__ pg, const float* __restrict__ pbeta,
        uint16_t* __restrict__ xout, float* __restrict__ ssc,
        unsigned* __restrict__ mmax, unsigned* __restrict__ mmin){
    __shared__ __align__(16) float sw[CIN * COUT];
    __shared__ float sb[COUT];
    __shared__ float sa[ACT ? 2*CIN : 1];
    __shared__ __align__(16) float sred[16 * 260];
    const int tid = threadIdx.x;
    for (int i = tid; i < CIN * COUT; i += 256) sw[i] = wt[i];
    if (tid < COUT) sb[tid] = bias[tid];
    if constexpr (ACT){
        if (tid < CIN){
            float s = 0.f, ss = 0.f;
#pragma unroll 4
            for (int k = 0; k < NBUCK; k++){ s += pssc[k*256 + tid]; ss += pssc[k*256 + 128 + tid]; }
            const float inv = 1.0f / NTOT;
            float mean = s * inv;
            float var  = ss * inv - mean * mean;
            float a = pg[tid] / sqrtf(var + 1e-5f);
            sa[tid] = a;
            sa[CIN + tid] = fmaf(-mean, a, pbeta[tid]);
        }
    }
    __syncthreads();
    const int b = blockIdx.x >> 7;
    const int ls = ((blockIdx.x & 127) << 8) + tid;
    float f[CIN];
    if constexpr (GATHER){
        const int s = ls >> 5;
        const int g = gidx[(size_t)b * LCOLS + ls];
        const float* px = xyz + (size_t)b * 3 * NPTS;
        const float cx = nx[b*3*NPOINT + s], cy = nx[b*3*NPOINT + NPOINT + s], cz = nx[b*3*NPOINT + 2*NPOINT + s];
        f[0] = sub_rn(px[g], cx); f[1] = sub_rn(px[NPTS+g], cy); f[2] = sub_rn(px[2*NPTS+g], cz);
        const u16x8* pr = (const u16x8*)(ptsT + ((size_t)b * NPTS + (size_t)g) * 64);
#pragma unroll
        for (int jj = 0; jj < 8; jj++){
            u16x8 v = pr[jj];
#pragma unroll
            for (int e = 0; e < 8; e++) f[3 + jj*8 + e] = bf2f(v[e]);
        }
    } else {
        const uint16_t* xp = xin + (size_t)b * CIN * LCOLS + ls;
#pragma unroll
        for (int c = 0; c < CIN; c++){
            float v = bf2f(xp[(size_t)c * LCOLS]);
            if constexpr (ACT) v = fmaxf(fmaf(sa[c], v, sa[CIN + c]), 0.0f);
            f[c] = v;
        }
    }
    uint16_t* op = xout + (size_t)b * COUT * LCOLS + ls;
    float* sbck = ssc + (blockIdx.x & (NBUCK-1)) * 256;
    for (int o0 = 0; o0 < COUT; o0 += 16){
        float acc[16];
#pragma unroll
        for (int j = 0; j < 16; j++) acc[j] = sb[o0 + j];
#pragma unroll
        for (int c = 0; c < CIN; c++){
            const float4* wr = (const float4*)(sw + c * COUT + o0);  // uniform -> LDS broadcast
            float4 w0_ = wr[0], w1_ = wr[1], w2_ = wr[2], w3_ = wr[3];
            const float fc = f[c];
            acc[0]  = fmaf(w0_.x, fc, acc[0]);  acc[1]  = fmaf(w0_.y, fc, acc[1]);
            acc[2]  = fmaf(w0_.z, fc, acc[2]);  acc[3]  = fmaf(w0_.w, fc, acc[3]);
            acc[4]  = fmaf(w1_.x, fc, acc[4]);  acc[5]  = fmaf(w1_.y, fc, acc[5]);
            acc[6]  = fmaf(w1_.z, fc, acc[6]);  acc[7]  = fmaf(w1_.w, fc, acc[7]);
            acc[8]  = fmaf(w2_.x, fc, acc[8]);  acc[9]  = fmaf(w2_.y, fc, acc[9]);
            acc[10] = fmaf(w2_.z, fc, acc[10]); acc[11] = fmaf(w2_.w, fc, acc[11]);
            acc[12] = fmaf(w3_.x, fc, acc[12]); acc[13] = fmaf(w3_.y, fc, acc[13]);
            acc[14] = fmaf(w3_.z, fc, acc[14]); acc[15] = fmaf(w3_.w, fc, acc[15]);
        }
        if constexpr (WRITE){
#pragma unroll
            for (int j = 0; j < 16; j++) op[(size_t)(o0 + j) * LCOLS] = f2bf(acc[j]);
        }
        // ---- block-level stats reduce on f32 accs ----
        __syncthreads();                       // protect sred reuse from previous group
#pragma unroll
        for (int k = 0; k < 16; k++) sred[k * 260 + tid] = acc[k];
        __syncthreads();
        const int ch = tid >> 4, seg = tid & 15;    // 16 ch x 16 segments of 16 cols
        float s = 0.f, ss = 0.f, mx = -1e30f, mn = 1e30f;
        const float4* rp = (const float4*)(sred + ch * 260 + seg * 16);
#pragma unroll
        for (int e = 0; e < 4; e++){
            float4 v = rp[e];
            s += v.x + v.y + v.z + v.w;
            ss = fmaf(v.x, v.x, ss); ss = fmaf(v.y, v.y, ss);
            ss = fmaf(v.z, v.z, ss); ss = fmaf(v.w, v.w, ss);
            if constexpr (MAXMIN){
                mx = fmaxf(mx, fmaxf(fmaxf(v.x, v.y), fmaxf(v.z, v.w)));
                mn = fminf(mn, fminf(fminf(v.x, v.y), fminf(v.z, v.w)));
            }
        }
#pragma unroll
        for (int off = 1; off < 16; off <<= 1){
            s += __shfl_xor(s, off); ss += __shfl_xor(ss, off);
            if constexpr (MAXMIN){ mx = fmaxf(mx, __shfl_xor(mx, off)); mn = fminf(mn, __shfl_xor(mn, off)); }
        }
        if (seg == 0){
            atomicAdd(&sbck[o0 + ch], s);
            atomicAdd(&sbck[128 + o0 + ch], ss);
            if constexpr (MAXMIN){
                atomicMax(&mmax[b * 128 + o0 + ch], fkey(mx));
                atomicMin(&mmin[b * 128 + o0 + ch], fkey(mn));
            }
        }
    }
}

// ---------- 4) finalize: out = relu(a * (a>=0 ? max : min) + c) per (b,ch) ----------
__global__ __launch_bounds__(64) void final_kernel(const float* __restrict__ ssc, const float* __restrict__ g2,
                                                   const float* __restrict__ be2, const unsigned* __restrict__ mmax,
                                                   const unsigned* __restrict__ mmin, float* __restrict__ out){
    const int t = blockIdx.x * 64 + threadIdx.x;   // 0..2047 : b*128+o
    const int o = t & 127;
    float s = 0.f, ss = 0.f;
    for (int k = 0; k < NBUCK; k++){ s += ssc[k*256 + o]; ss += ssc[k*256 + 128 + o]; }
    const float inv = 1.0f / NTOT;
    float mean = s * inv;
    float var  = ss * inv - mean * mean;
    float a = g2[o] / sqrtf(var + 1e-5f);
    float c = fmaf(-mean, a, be2[o]);
    unsigned k = (a >= 0.f) ? mmax[t] : mmin[t];   // relu(a*x+c) monotone in x, direction sign(a)
    float x = funkey(k);
    out[49152 + t] = fmaxf(fmaf(a, x, c), 0.0f);
}

extern "C" void kernel_launch(void* const* d_in, const int* in_sizes, int n_in,
                              void* d_out, int out_size, void* d_ws, size_t ws_size,
                              hipStream_t stream){
    const float* xyz = (const float*)d_in[0];
    const float* pts = (const float*)d_in[1];
    const float* w0  = (const float*)d_in[2];  const float* b0  = (const float*)d_in[3];
    const float* g0  = (const float*)d_in[4];  const float* be0 = (const float*)d_in[5];
    const float* w1  = (const float*)d_in[6];  const float* b1  = (const float*)d_in[7];
    const float* g1  = (const float*)d_in[8];  const float* be1 = (const float*)d_in[9];
    const float* w2  = (const float*)d_in[10]; const float* b2  = (const float*)d_in[11];
    const float* g2  = (const float*)d_in[12]; const float* be2 = (const float*)d_in[13];
    float* out = (float*)d_out;
    char* ws = (char*)d_ws;

    int*      fps_idx = (int*)(ws + OFF_FPS);
    int*      gidx    = (int*)(ws + OFF_GIDX);
    float*    ssc0    = (float*)(ws + OFF_SSC);            // 32*256 each
    float*    ssc1    = ssc0 + NBUCK*256;
    float*    ssc2    = ssc1 + NBUCK*256;
    unsigned* mmax    = (unsigned*)(ws + OFF_MM);
    unsigned* mmin    = mmax + 2048;
    float*    wt0     = (float*)(ws + OFF_WT);
    float*    wt1     = wt0 + 67*64;
    float*    wt2     = wt1 + 64*64;
    uint16_t* t0      = (uint16_t*)(ws + OFF_T0);
    uint16_t* t1      = (uint16_t*)(ws + OFF_T1);
    uint16_t* ptsT    = (uint16_t*)(ws + OFF_PTST);

    hipMemsetAsync(ws + OFF_SSC, 0, 3 * NBUCK * 256 * 4, stream);
    hipMemsetAsync(ws + OFF_MM, 0x00, 8192, stream);          // key 0 < key(-inf)
    hipMemsetAsync(ws + OFF_MM + 8192, 0xFF, 8192, stream);   // key ~0 > key(+inf)

    fps_fused_kernel<<<2080, 512, 0, stream>>>(xyz, fps_idx, out, pts, ptsT,
                                               w0, w1, w2, wt0, wt1, wt2);
    ballquery_kernel<<<4096, 256, 0, stream>>>(xyz, fps_idx, gidx);

    mm_kernel<67, 64, false, true, true, false><<<2048, 256, 0, stream>>>(
        nullptr, xyz, out, ptsT, gidx, wt0, b0, nullptr, nullptr, nullptr, t0, ssc0, nullptr, nullptr);

    mm_kernel<64, 64, true, false, true, false><<<2048, 256, 0, stream>>>(
        t0, nullptr, nullptr, nullptr, nullptr, wt1, b1, ssc0, g0, be0, t1, ssc1, nullptr, nullptr);

    mm_kernel<64, 128, true, false, false, true><<<2048, 256, 0, stream>>>(
        t1, nullptr, nullptr, nullptr, nullptr, wt2, b2, ssc1, g1, be1, nullptr, ssc2, mmax, mmin);

    final_kernel<<<32, 64, 0, stream>>>(ssc2, g2, be2, mmax, mmin, out);
}

// Round 13
// 1342.387 us; speedup vs baseline: 1.0793x; 1.0571x over previous
//
#include <hip/hip_runtime.h>
#include <stdint.h>
#include <limits.h>

// ---------- exact-rounding helpers (block FMA contraction; match numpy op order) ----------
__device__ inline float mul_rn(float a, float b){ float r; asm("v_mul_f32 %0, %1, %2" : "=v"(r) : "v"(a), "v"(b)); return r; }
__device__ inline float add_rn(float a, float b){ float r; asm("v_add_f32 %0, %1, %2" : "=v"(r) : "v"(a), "v"(b)); return r; }
__device__ inline float sub_rn(float a, float b){ float r; asm("v_sub_f32 %0, %1, %2" : "=v"(r) : "v"(a), "v"(b)); return r; }

typedef uint16_t u16x8 __attribute__((ext_vector_type(8)));
typedef float    f32x2 __attribute__((ext_vector_type(2)));

__device__ inline float bf2f(uint16_t u){ return __uint_as_float(((uint32_t)u) << 16); }
__device__ inline uint16_t f2bf(float f){
    uint32_t u = __float_as_uint(f);
    u += 0x7fffu + ((u >> 16) & 1u);   // RNE
    return (uint16_t)(u >> 16);
}
// monotonic uint key for float (total order): k(f) increasing in f
__device__ inline unsigned fkey(float f){
    unsigned u = __float_as_uint(f);
    return (u & 0x80000000u) ? ~u : (u | 0x80000000u);
}
__device__ inline float funkey(unsigned k){
    unsigned u = (k & 0x80000000u) ? (k ^ 0x80000000u) : ~k;
    return __uint_as_float(u);
}

// full-wave u32 max via DPP builtins (compiler inserts hazard waits). Valid in lane 63.
__device__ inline unsigned dpp_umax_wave(unsigned v){
    unsigned t;
    t = (unsigned)__builtin_amdgcn_update_dpp((int)v, (int)v, 0x111, 0xf, 0xf, false); v = v > t ? v : t; // row_shr:1
    t = (unsigned)__builtin_amdgcn_update_dpp((int)v, (int)v, 0x112, 0xf, 0xf, false); v = v > t ? v : t; // row_shr:2
    t = (unsigned)__builtin_amdgcn_update_dpp((int)v, (int)v, 0x114, 0xf, 0xf, false); v = v > t ? v : t; // row_shr:4
    t = (unsigned)__builtin_amdgcn_update_dpp((int)v, (int)v, 0x118, 0xf, 0xf, false); v = v > t ? v : t; // row_shr:8
    t = (unsigned)__builtin_amdgcn_update_dpp((int)v, (int)v, 0x142, 0xf, 0xf, false); v = v > t ? v : t; // row_bcast:15
    t = (unsigned)__builtin_amdgcn_update_dpp((int)v, (int)v, 0x143, 0xf, 0xf, false); v = v > t ? v : t; // row_bcast:31
    return v;
}

#define NPTS   8192
#define NBATCH 16
#define NPOINT 1024
#define NSAMP  32
#define LCOLS  32768          // NPOINT*NSAMP
#define NTOT   524288.0f      // 16*32768
#define NBUCK  32

// ---------- workspace layout (bytes) ----------
#define OFF_FPS   0u               // 16*1024*4 = 65536
#define OFF_GIDX  65536u           // 16*1024*32*4 = 2097152
#define OFF_SSC   2162688u         // 3 layers * 32 buckets * 256 f32 = 98304
#define OFF_MM    2263040u         // mmax 2048 u32 ; mmin 2048 u32 = 16384
#define OFF_WT    2279424u         // 66304
#define OFF_T0    4194304u         // 67108864
#define OFF_T1    71303168u        // 67108864
#define OFF_PTST  138412032u       // 16777216 (end 155189248)

// ---------- 1) FUSED (512 thr/block): fps (0..15) + pts transpose (16..2063) + prep (2064..2079) ----------
__global__ __launch_bounds__(512) void fps_fused_kernel(const float* __restrict__ xyz,
        int* __restrict__ fps_idx, float* __restrict__ out_xyz,
        const float* __restrict__ pts, uint16_t* __restrict__ ptsT,
        const float* __restrict__ w0, const float* __restrict__ w1, const float* __restrict__ w2,
        float* __restrict__ wt0, float* __restrict__ wt1, float* __restrict__ wt2){
#pragma clang fp contract(off)
    __shared__ __align__(16) float smem[33824];   // sxyz4 32768 + wslots 32 + sidx 1024
    const int bid = blockIdx.x, tid = threadIdx.x;

    if (bid >= 2064){                      // ---- prep path: wt[c][o] transposes ----
        int t = (bid - 2064) * 512 + tid;  // 0..8191
        if (t < 64*67){ int o = t / 67, c = t % 67; wt0[c*64 + o] = w0[t]; }
        if (t < 64*64){ int o = t >> 6, c = t & 63; wt1[c*64 + o] = w1[t]; }
        if (t < 128*64){ int o = t >> 6, c = t & 63; wt2[c*128 + o] = w2[t]; }
        return;
    }
    if (bid >= 16){                        // ---- transpose path: (B,64,N)f32 -> (B,N,64)bf16 ----
        float (*tile)[65] = (float(*)[65])smem;
        const int tb = bid - 16;
        const int bt = tb >> 7, n0 = (tb & 127) << 6;
        const int tn = tid & 63, tg = tid >> 6;             // tg 0..7, 8 c's each
        const float* src = pts + (size_t)bt * 64 * NPTS + n0;
#pragma unroll
        for (int i = 0; i < 8; i++){ int c = tg*8 + i; tile[c][tn] = src[(size_t)c * NPTS + tn]; }
        __syncthreads();
        uint16_t* dst = ptsT + ((size_t)bt * NPTS + n0) * 64;
#pragma unroll
        for (int i = 0; i < 8; i++){ int n = tg*8 + i; dst[(size_t)n * 64 + tn] = f2bf(tile[tn][n]); }
        return;
    }

    // ---- fps path: 512 threads (2 waves/SIMD), 16 points/thread ----
    // EXACT arithmetic (R12 lesson: selection margins < 2e-7; only numpy-order
    // subtract-square is safe). f32x2 C-vectors: LLVM may select v_pk_add/mul_f32
    // (per-component RNE, same op order — bit-identical either way).
    float* sxyz = smem;                                                 // [8192*4] xyz pad
    float4* sxyz4 = (float4*)smem;
    unsigned long long* wslots = (unsigned long long*)(smem + 32768);   // [2*8] = floats 32768..32800
    int* sidx = (int*)(smem + 32800);                                   // [1024] floats 32800..33824
    const int b = bid;
    const float* px = xyz + (size_t)b * 3 * NPTS;
    for (int i = tid; i < NPTS; i += 512)
        sxyz4[i] = float4{px[i], px[NPTS + i], px[2*NPTS + i], 0.f};
    __syncthreads();

    const int p0 = tid << 4;
    const float4* rp = sxyz4 + p0;
    f32x2 X2[8], Y2[8], Z2[8], M2[8];
#pragma unroll
    for (int j = 0; j < 8; j++){
        float4 qa = rp[2*j], qb = rp[2*j + 1];
        X2[j] = f32x2{qa.x, qb.x};
        Y2[j] = f32x2{qa.y, qb.y};
        Z2[j] = f32x2{qa.z, qb.z};
        M2[j] = f32x2{1e10f, 1e10f};
    }
    const unsigned base = ~(unsigned)p0;          // ~(p0+j) == base - j

    int cur = 0;
    float cx = sxyz[0], cy = sxyz[1], cz = sxyz[2];
    for (int t = 0; t < NPOINT; t++){
        if (tid == 0) sidx[t] = cur;               // record this iteration's centroid
        const f32x2 c2x = f32x2{cx, cx}, c2y = f32x2{cy, cy}, c2z = f32x2{cz, cz};
#pragma unroll
        for (int j = 0; j < 8; j++){
            f32x2 dx = X2[j] - c2x;
            f32x2 dy = Y2[j] - c2y;
            f32x2 dz = Z2[j] - c2z;
            f32x2 d2 = dx*dx + dy*dy + dz*dz;      // contract(off): per-op RNE, numpy order
            M2[j].x = fminf(M2[j].x, d2.x);
            M2[j].y = fminf(M2[j].y, d2.y);
        }
        float tv[8];
#pragma unroll
        for (int j = 0; j < 8; j++) tv[j] = fmaxf(M2[j].x, M2[j].y);
        float t0_ = fmaxf(fmaxf(tv[0], tv[1]), fmaxf(tv[2], tv[3]));
        float t1_ = fmaxf(fmaxf(tv[4], tv[5]), fmaxf(tv[6], tv[7]));
        const float mt = fmaxf(t0_, t1_);
        // smallest owned position with M==mt (descending scan -> smallest j wins)
        unsigned jpos = 0;
#pragma unroll
        for (int j = 7; j >= 0; j--){
            if (M2[j].y == mt) jpos = 2*j + 1;
            if (M2[j].x == mt) jpos = 2*j;
        }
        const unsigned lo = base - jpos;           // == ~(p0 + jpos)
        const unsigned mtu = __float_as_uint(mt);  // d2>=0 -> uint order == float order
        unsigned vm = dpp_umax_wave(mtu);
        const unsigned wvu = __builtin_amdgcn_readlane(vm, 63);
        unsigned long long cand = __ballot(mtu == wvu);
        const int fl = __ffsll((long long)cand) - 1;        // lowest lane = smallest p
        const unsigned wlo = __builtin_amdgcn_readlane(lo, fl);
        if ((tid & 63) == 0)
            wslots[(t & 1) * 8 + (tid >> 6)] = (((unsigned long long)wvu) << 32) | wlo;
        __syncthreads();                            // the ONLY barrier per iter
        const ulonglong2* sp = (const ulonglong2*)(wslots + (t & 1) * 8);
        ulonglong2 ka = sp[0], kb = sp[1], kc = sp[2], kd = sp[3];   // 4 uniform b128 reads
        unsigned long long ma = (ka.y > ka.x) ? ka.y : ka.x;
        unsigned long long mb = (kb.y > kb.x) ? kb.y : kb.x;
        unsigned long long mc = (kc.y > kc.x) ? kc.y : kc.x;
        unsigned long long md = (kd.y > kd.x) ? kd.y : kd.x;
        unsigned long long mab = (mb > ma) ? mb : ma;
        unsigned long long mcd = (md > mc) ? md : mc;
        unsigned long long win = (mcd > mab) ? mcd : mab;
        cur = (int)(~((unsigned)win));
        const float4 cc4 = sxyz4[cur];              // single uniform b128 read
        cx = cc4.x; cy = cc4.y; cz = cc4.z;
    }
    __syncthreads();
    // output phase: 2 per thread
#pragma unroll
    for (int q = 0; q < 2; q++){
        const int i = (q << 9) + tid;
        const int idx = sidx[i];
        fps_idx[b * NPOINT + i] = idx;
        const float4 c4 = sxyz4[idx];
        float* oxp = out_xyz + b * 3 * NPOINT;
        oxp[i]            = c4.x;
        oxp[NPOINT + i]   = c4.y;
        oxp[2*NPOINT + i] = c4.z;
    }
}

// ---------- 2) ball query: one wave per (b,s) ----------
__global__ __launch_bounds__(256) void ballquery_kernel(const float* __restrict__ xyz,
                                                        const int* __restrict__ fps_idx, int* __restrict__ gidx){
    const int w = (blockIdx.x << 2) + (threadIdx.x >> 6);
    const int lane = threadIdx.x & 63;
    const int b = w >> 10, s = w & 1023;
    const float* px = xyz + (size_t)b * 3 * NPTS;
    const int ci = fps_idx[b * NPOINT + s];
    const float cx = px[ci], cy = px[NPTS+ci], cz = px[2*NPTS+ci];
    int* gout = gidx + (size_t)b * LCOLS + s * NSAMP;
    int have = 0, first_p = 0; bool got = false;
    for (int c0 = 0; c0 < NPTS; c0 += 64){
        int p = c0 + lane;
        float dx = sub_rn(px[p], cx), dy = sub_rn(px[NPTS+p], cy), dz = sub_rn(px[2*NPTS+p], cz);
        float d2 = add_rn(add_rn(mul_rn(dx,dx), mul_rn(dy,dy)), mul_rn(dz,dz));
        bool in = (d2 <= 0.01f);
        unsigned long long m = __ballot(in);
        if (m && !got){ first_p = c0 + __ffsll(m) - 1; got = true; }
        if (in){
            int pos = have + __popcll(m & ((1ull << lane) - 1ull));
            if (pos < NSAMP) gout[pos] = p;
        }
        have += __popcll(m);
        if (have >= NSAMP) break;
    }
    for (int pos = have + lane; pos < NSAMP; pos += 64) gout[pos] = first_p;
}

// ---------- 3) fused conv+BN-stats kernel; BN params computed per-block from prev-layer sums ----------
template<int CIN, int COUT, bool ACT, bool GATHER, bool WRITE, bool MAXMIN>
__global__ __launch_bounds__(256) void mm_kernel(const uint16_t* __restrict__ xin,
        const float* __restrict__ xyz, const float* __restrict__ nx,
        const uint16_t* __restrict__ ptsT, const int* __restrict__ gidx,
        const float* __restrict__ wt, const float* __restrict__ bias,
        const float* __restrict__ pssc, const float* __restrict__ pg, const float* __restrict__ pbeta,
        uint16_t* __restrict__ xout, float* __restrict__ ssc,
        unsigned* __restrict__ mmax, unsigned* __restrict__ mmin){
    __shared__ __align__(16) float sw[CIN * COUT];
    __shared__ float sb[COUT];
    __shared__ float sa[ACT ? 2*CIN : 1];
    __shared__ __align__(16) float sred[16 * 260];
    const int tid = threadIdx.x;
    for (int i = tid; i < CIN * COUT; i += 256) sw[i] = wt[i];
    if (tid < COUT) sb[tid] = bias[tid];
    if constexpr (ACT){
        if (tid < CIN){
            float s = 0.f, ss = 0.f;
#pragma unroll 4
            for (int k = 0; k < NBUCK; k++){ s += pssc[k*256 + tid]; ss += pssc[k*256 + 128 + tid]; }
            const float inv = 1.0f / NTOT;
            float mean = s * inv;
            float var  = ss * inv - mean * mean;
            float a = pg[tid] / sqrtf(var + 1e-5f);
            sa[tid] = a;
            sa[CIN + tid] = fmaf(-mean, a, pbeta[tid]);
        }
    }
    __syncthreads();
    const int b = blockIdx.x >> 7;
    const int ls = ((blockIdx.x & 127) << 8) + tid;
    float f[CIN];
    if constexpr (GATHER){
        const int s = ls >> 5;
        const int g = gidx[(size_t)b * LCOLS + ls];
        const float* px = xyz + (size_t)b * 3 * NPTS;
        const float cx = nx[b*3*NPOINT + s], cy = nx[b*3*NPOINT + NPOINT + s], cz = nx[b*3*NPOINT + 2*NPOINT + s];
        f[0] = sub_rn(px[g], cx); f[1] = sub_rn(px[NPTS+g], cy); f[2] = sub_rn(px[2*NPTS+g], cz);
        const u16x8* pr = (const u16x8*)(ptsT + ((size_t)b * NPTS + (size_t)g) * 64);
#pragma unroll
        for (int jj = 0; jj < 8; jj++){
            u16x8 v = pr[jj];
#pragma unroll
            for (int e = 0; e < 8; e++) f[3 + jj*8 + e] = bf2f(v[e]);
        }
    } else {
        const uint16_t* xp = xin + (size_t)b * CIN * LCOLS + ls;
#pragma unroll
        for (int c = 0; c < CIN; c++){
            float v = bf2f(xp[(size_t)c * LCOLS]);
            if constexpr (ACT) v = fmaxf(fmaf(sa[c], v, sa[CIN + c]), 0.0f);
            f[c] = v;
        }
    }
    uint16_t* op = xout + (size_t)b * COUT * LCOLS + ls;
    float* sbck = ssc + (blockIdx.x & (NBUCK-1)) * 256;
    for (int o0 = 0; o0 < COUT; o0 += 16){
        float acc[16];
#pragma unroll
        for (int j = 0; j < 16; j++) acc[j] = sb[o0 + j];
#pragma unroll
        for (int c = 0; c < CIN; c++){
            const float4* wr = (const float4*)(sw + c * COUT + o0);  // uniform -> LDS broadcast
            float4 w0_ = wr[0], w1_ = wr[1], w2_ = wr[2], w3_ = wr[3];
            const float fc = f[c];
            acc[0]  = fmaf(w0_.x, fc, acc[0]);  acc[1]  = fmaf(w0_.y, fc, acc[1]);
            acc[2]  = fmaf(w0_.z, fc, acc[2]);  acc[3]  = fmaf(w0_.w, fc, acc[3]);
            acc[4]  = fmaf(w1_.x, fc, acc[4]);  acc[5]  = fmaf(w1_.y, fc, acc[5]);
            acc[6]  = fmaf(w1_.z, fc, acc[6]);  acc[7]  = fmaf(w1_.w, fc, acc[7]);
            acc[8]  = fmaf(w2_.x, fc, acc[8]);  acc[9]  = fmaf(w2_.y, fc, acc[9]);
            acc[10] = fmaf(w2_.z, fc, acc[10]); acc[11] = fmaf(w2_.w, fc, acc[11]);
            acc[12] = fmaf(w3_.x, fc, acc[12]); acc[13] = fmaf(w3_.y, fc, acc[13]);
            acc[14] = fmaf(w3_.z, fc, acc[14]); acc[15] = fmaf(w3_.w, fc, acc[15]);
        }
        if constexpr (WRITE){
#pragma unroll
            for (int j = 0; j < 16; j++) op[(size_t)(o0 + j) * LCOLS] = f2bf(acc[j]);
        }
        // ---- block-level stats reduce on f32 accs ----
        __syncthreads();                       // protect sred reuse from previous group
#pragma unroll
        for (int k = 0; k < 16; k++) sred[k * 260 + tid] = acc[k];
        __syncthreads();
        const int ch = tid >> 4, seg = tid & 15;    // 16 ch x 16 segments of 16 cols
        float s = 0.f, ss = 0.f, mx = -1e30f, mn = 1e30f;
        const float4* rp = (const float4*)(sred + ch * 260 + seg * 16);
#pragma unroll
        for (int e = 0; e < 4; e++){
            float4 v = rp[e];
            s += v.x + v.y + v.z + v.w;
            ss = fmaf(v.x, v.x, ss); ss = fmaf(v.y, v.y, ss);
            ss = fmaf(v.z, v.z, ss); ss = fmaf(v.w, v.w, ss);
            if constexpr (MAXMIN){
                mx = fmaxf(mx, fmaxf(fmaxf(v.x, v.y), fmaxf(v.z, v.w)));
                mn = fminf(mn, fminf(fminf(v.x, v.y), fminf(v.z, v.w)));
            }
        }
#pragma unroll
        for (int off = 1; off < 16; off <<= 1){
            s += __shfl_xor(s, off); ss += __shfl_xor(ss, off);
            if constexpr (MAXMIN){ mx = fmaxf(mx, __shfl_xor(mx, off)); mn = fminf(mn, __shfl_xor(mn, off)); }
        }
        if (seg == 0){
            atomicAdd(&sbck[o0 + ch], s);
            atomicAdd(&sbck[128 + o0 + ch], ss);
            if constexpr (MAXMIN){
                atomicMax(&mmax[b * 128 + o0 + ch], fkey(mx));
                atomicMin(&mmin[b * 128 + o0 + ch], fkey(mn));
            }
        }
    }
}

// ---------- 4) finalize: out = relu(a * (a>=0 ? max : min) + c) per (b,ch) ----------
__global__ __launch_bounds__(64) void final_kernel(const float* __restrict__ ssc, const float* __restrict__ g2,
                                                   const float* __restrict__ be2, const unsigned* __restrict__ mmax,
                                                   const unsigned* __restrict__ mmin, float* __restrict__ out){
    const int t = blockIdx.x * 64 + threadIdx.x;   // 0..2047 : b*128+o
    const int o = t & 127;
    float s = 0.f, ss = 0.f;
    for (int k = 0; k < NBUCK; k++){ s += ssc[k*256 + o]; ss += ssc[k*256 + 128 + o]; }
    const float inv = 1.0f / NTOT;
    float mean = s * inv;
    float var  = ss * inv - mean * mean;
    float a = g2[o] / sqrtf(var + 1e-5f);
    float c = fmaf(-mean, a, be2[o]);
    unsigned k = (a >= 0.f) ? mmax[t] : mmin[t];   // relu(a*x+c) monotone in x, direction sign(a)
    float x = funkey(k);
    out[49152 + t] = fmaxf(fmaf(a, x, c), 0.0f);
}

extern "C" void kernel_launch(void* const* d_in, const int* in_sizes, int n_in,
                              void* d_out, int out_size, void* d_ws, size_t ws_size,
                              hipStream_t stream){
    const float* xyz = (const float*)d_in[0];
    const float* pts = (const float*)d_in[1];
    const float* w0  = (const float*)d_in[2];  const float* b0  = (const float*)d_in[3];
    const float* g0  = (const float*)d_in[4];  const float* be0 = (const float*)d_in[5];
    const float* w1  = (const float*)d_in[6];  const float* b1  = (const float*)d_in[7];
    const float* g1  = (const float*)d_in[8];  const float* be1 = (const float*)d_in[9];
    const float* w2  = (const float*)d_in[10]; const float* b2  = (const float*)d_in[11];
    const float* g2  = (const float*)d_in[12]; const float* be2 = (const float*)d_in[13];
    float* out = (float*)d_out;
    char* ws = (char*)d_ws;

    int*      fps_idx = (int*)(ws + OFF_FPS);
    int*      gidx    = (int*)(ws + OFF_GIDX);
    float*    ssc0    = (float*)(ws + OFF_SSC);            // 32*256 each
    float*    ssc1    = ssc0 + NBUCK*256;
    float*    ssc2    = ssc1 + NBUCK*256;
    unsigned* mmax    = (unsigned*)(ws + OFF_MM);
    unsigned* mmin    = mmax + 2048;
    float*    wt0     = (float*)(ws + OFF_WT);
    float*    wt1     = wt0 + 67*64;
    float*    wt2     = wt1 + 64*64;
    uint16_t* t0      = (uint16_t*)(ws + OFF_T0);
    uint16_t* t1      = (uint16_t*)(ws + OFF_T1);
    uint16_t* ptsT    = (uint16_t*)(ws + OFF_PTST);

    hipMemsetAsync(ws + OFF_SSC, 0, 3 * NBUCK * 256 * 4, stream);
    hipMemsetAsync(ws + OFF_MM, 0x00, 8192, stream);          // key 0 < key(-inf)
    hipMemsetAsync(ws + OFF_MM + 8192, 0xFF, 8192, stream);   // key ~0 > key(+inf)

    fps_fused_kernel<<<2080, 512, 0, stream>>>(xyz, fps_idx, out, pts, ptsT,
                                               w0, w1, w2, wt0, wt1, wt2);
    ballquery_kernel<<<4096, 256, 0, stream>>>(xyz, fps_idx, gidx);

    mm_kernel<67, 64, false, true, true, false><<<2048, 256, 0, stream>>>(
        nullptr, xyz, out, ptsT, gidx, wt0, b0, nullptr, nullptr, nullptr, t0, ssc0, nullptr, nullptr);

    mm_kernel<64, 64, true, false, true, false><<<2048, 256, 0, stream>>>(
        t0, nullptr, nullptr, nullptr, nullptr, wt1, b1, ssc0, g0, be0, t1, ssc1, nullptr, nullptr);

    mm_kernel<64, 128, true, false, false, true><<<2048, 256, 0, stream>>>(
        t1, nullptr, nullptr, nullptr, nullptr, wt2, b2, ssc1, g1, be1, nullptr, ssc2, mmax, mmin);

    final_kernel<<<32, 64, 0, stream>>>(ssc2, g2, be2, mmax, mmin, out);
}

// Round 14
// 1214.225 us; speedup vs baseline: 1.1933x; 1.1056x over previous
//
#include <hip/hip_runtime.h>
#include <stdint.h>
#include <limits.h>

// ---------- exact-rounding helpers (match numpy op order; used in selection kernels) ----------
__device__ inline float mul_rn(float a, float b){ float r; asm("v_mul_f32 %0, %1, %2" : "=v"(r) : "v"(a), "v"(b)); return r; }
__device__ inline float add_rn(float a, float b){ float r; asm("v_add_f32 %0, %1, %2" : "=v"(r) : "v"(a), "v"(b)); return r; }
__device__ inline float sub_rn(float a, float b){ float r; asm("v_sub_f32 %0, %1, %2" : "=v"(r) : "v"(a), "v"(b)); return r; }

typedef uint16_t u16x8 __attribute__((ext_vector_type(8)));
typedef float    f32x2 __attribute__((ext_vector_type(2)));
typedef short    bf16x8 __attribute__((ext_vector_type(8)));
typedef float    fx4 __attribute__((ext_vector_type(4)));

__device__ inline float bf2f(uint16_t u){ return __uint_as_float(((uint32_t)u) << 16); }
__device__ inline uint16_t f2bf(float f){
    uint32_t u = __float_as_uint(f);
    u += 0x7fffu + ((u >> 16) & 1u);   // RNE
    return (uint16_t)(u >> 16);
}
__device__ inline unsigned fkey(float f){
    unsigned u = __float_as_uint(f);
    return (u & 0x80000000u) ? ~u : (u | 0x80000000u);
}
__device__ inline float funkey(unsigned k){
    unsigned u = (k & 0x80000000u) ? (k ^ 0x80000000u) : ~k;
    return __uint_as_float(u);
}

// full-wave u32 max via DPP builtins (compiler inserts hazard waits). Valid in lane 63.
__device__ inline unsigned dpp_umax_wave(unsigned v){
    unsigned t;
    t = (unsigned)__builtin_amdgcn_update_dpp((int)v, (int)v, 0x111, 0xf, 0xf, false); v = v > t ? v : t;
    t = (unsigned)__builtin_amdgcn_update_dpp((int)v, (int)v, 0x112, 0xf, 0xf, false); v = v > t ? v : t;
    t = (unsigned)__builtin_amdgcn_update_dpp((int)v, (int)v, 0x114, 0xf, 0xf, false); v = v > t ? v : t;
    t = (unsigned)__builtin_amdgcn_update_dpp((int)v, (int)v, 0x118, 0xf, 0xf, false); v = v > t ? v : t;
    t = (unsigned)__builtin_amdgcn_update_dpp((int)v, (int)v, 0x142, 0xf, 0xf, false); v = v > t ? v : t;
    t = (unsigned)__builtin_amdgcn_update_dpp((int)v, (int)v, 0x143, 0xf, 0xf, false); v = v > t ? v : t;
    return v;
}

#define NPTS   8192
#define NBATCH 16
#define NPOINT 1024
#define NSAMP  32
#define LCOLS  32768          // NPOINT*NSAMP
#define NTOT   524288.0f      // 16*32768
#define NBUCK  32

// ---------- workspace layout (bytes) ----------
#define OFF_FPS   0u               // 16*1024*4 = 65536
#define OFF_GIDX  65536u           // 16*1024*32*4 = 2097152
#define OFF_SSC   2162688u         // 3 layers * 32 buckets * 256 f32 = 98304
#define OFF_MM    2263040u         // mmax 2048 u32 ; mmin 2048 u32 = 16384
#define OFF_WT    2279424u         // wt0 4288 f32 = 17152
#define OFF_WPK1  2345728u         // 4096 u16 = 8192
#define OFF_WPK2  2353920u         // 8192 u16 = 16384 (end 2370304)
#define OFF_T0    4194304u         // 67108864
#define OFF_T1    71303168u        // 67108864
#define OFF_PTST  138412032u       // 16777216 (end 155189248)

// ---------- 1) FUSED (512 thr/block): fps (0..15) + pts transpose (16..2063) + prep (2064..2079) ----------
__global__ __launch_bounds__(512) void fps_fused_kernel(const float* __restrict__ xyz,
        int* __restrict__ fps_idx, float* __restrict__ out_xyz,
        const float* __restrict__ pts, uint16_t* __restrict__ ptsT,
        const float* __restrict__ w0, const float* __restrict__ w1, const float* __restrict__ w2,
        float* __restrict__ wt0, uint16_t* __restrict__ wpk1, uint16_t* __restrict__ wpk2){
#pragma clang fp contract(off)
    __shared__ __align__(16) float smem[33824];   // sxyz4 32768 + wslots 32 + sidx 1024
    const int bid = blockIdx.x, tid = threadIdx.x;

    if (bid >= 2064){                      // ---- prep path ----
        int t = (bid - 2064) * 512 + tid;  // 0..8191
        if (t < 64*67){ int o = t / 67, c = t % 67; wt0[c*64 + o] = w0[t]; }
        if (t < 64*64){ int o = t >> 6, c = t & 63; wpk1[((c>>3)*64  + o)*8 + (c&7)] = f2bf(w1[t]); }
        if (t < 128*64){ int o = t >> 6, c = t & 63; wpk2[((c>>3)*128 + o)*8 + (c&7)] = f2bf(w2[t]); }
        return;
    }
    if (bid >= 16){                        // ---- transpose path: (B,64,N)f32 -> (B,N,64)bf16 ----
        float (*tile)[65] = (float(*)[65])smem;
        const int tb = bid - 16;
        const int bt = tb >> 7, n0 = (tb & 127) << 6;
        const int tn = tid & 63, tg = tid >> 6;             // tg 0..7, 8 c's each
        const float* src = pts + (size_t)bt * 64 * NPTS + n0;
#pragma unroll
        for (int i = 0; i < 8; i++){ int c = tg*8 + i; tile[c][tn] = src[(size_t)c * NPTS + tn]; }
        __syncthreads();
        uint16_t* dst = ptsT + ((size_t)bt * NPTS + n0) * 64;
#pragma unroll
        for (int i = 0; i < 8; i++){ int n = tg*8 + i; dst[(size_t)n * 64 + tn] = f2bf(tile[tn][n]); }
        return;
    }

    // ---- fps path: 512 threads (2 waves/SIMD), 16 points/thread, EXACT numpy-order arithmetic ----
    float* sxyz = smem;
    float4* sxyz4 = (float4*)smem;
    unsigned long long* wslots = (unsigned long long*)(smem + 32768);   // [2*8]
    int* sidx = (int*)(smem + 32800);                                   // [1024]
    const int b = bid;
    const float* px = xyz + (size_t)b * 3 * NPTS;
    for (int i = tid; i < NPTS; i += 512)
        sxyz4[i] = float4{px[i], px[NPTS + i], px[2*NPTS + i], 0.f};
    __syncthreads();

    const int p0 = tid << 4;
    const float4* rp = sxyz4 + p0;
    f32x2 X2[8], Y2[8], Z2[8], M2[8];
#pragma unroll
    for (int j = 0; j < 8; j++){
        float4 qa = rp[2*j], qb = rp[2*j + 1];
        X2[j] = f32x2{qa.x, qb.x};
        Y2[j] = f32x2{qa.y, qb.y};
        Z2[j] = f32x2{qa.z, qb.z};
        M2[j] = f32x2{1e10f, 1e10f};
    }
    const unsigned base = ~(unsigned)p0;

    int cur = 0;
    float cx = sxyz[0], cy = sxyz[1], cz = sxyz[2];
    for (int t = 0; t < NPOINT; t++){
        if (tid == 0) sidx[t] = cur;
        const f32x2 c2x = f32x2{cx, cx}, c2y = f32x2{cy, cy}, c2z = f32x2{cz, cz};
#pragma unroll
        for (int j = 0; j < 8; j++){
            f32x2 dx = X2[j] - c2x;
            f32x2 dy = Y2[j] - c2y;
            f32x2 dz = Z2[j] - c2z;
            f32x2 d2 = dx*dx + dy*dy + dz*dz;      // contract(off): per-op RNE, numpy order
            M2[j].x = fminf(M2[j].x, d2.x);
            M2[j].y = fminf(M2[j].y, d2.y);
        }
        float tv[8];
#pragma unroll
        for (int j = 0; j < 8; j++) tv[j] = fmaxf(M2[j].x, M2[j].y);
        float t0_ = fmaxf(fmaxf(tv[0], tv[1]), fmaxf(tv[2], tv[3]));
        float t1_ = fmaxf(fmaxf(tv[4], tv[5]), fmaxf(tv[6], tv[7]));
        const float mt = fmaxf(t0_, t1_);
        unsigned jpos = 0;
#pragma unroll
        for (int j = 7; j >= 0; j--){
            if (M2[j].y == mt) jpos = 2*j + 1;
            if (M2[j].x == mt) jpos = 2*j;
        }
        const unsigned lo = base - jpos;
        const unsigned mtu = __float_as_uint(mt);
        unsigned vm = dpp_umax_wave(mtu);
        const unsigned wvu = __builtin_amdgcn_readlane(vm, 63);
        unsigned long long cand = __ballot(mtu == wvu);
        const int fl = __ffsll((long long)cand) - 1;
        const unsigned wlo = __builtin_amdgcn_readlane(lo, fl);
        if ((tid & 63) == 0)
            wslots[(t & 1) * 8 + (tid >> 6)] = (((unsigned long long)wvu) << 32) | wlo;
        __syncthreads();
        const ulonglong2* sp = (const ulonglong2*)(wslots + (t & 1) * 8);
        ulonglong2 ka = sp[0], kb = sp[1], kc = sp[2], kd = sp[3];
        unsigned long long ma = (ka.y > ka.x) ? ka.y : ka.x;
        unsigned long long mb = (kb.y > kb.x) ? kb.y : kb.x;
        unsigned long long mc = (kc.y > kc.x) ? kc.y : kc.x;
        unsigned long long md = (kd.y > kd.x) ? kd.y : kd.x;
        unsigned long long mab = (mb > ma) ? mb : ma;
        unsigned long long mcd = (md > mc) ? md : mc;
        unsigned long long win = (mcd > mab) ? mcd : mab;
        cur = (int)(~((unsigned)win));
        const float4 cc4 = sxyz4[cur];
        cx = cc4.x; cy = cc4.y; cz = cc4.z;
    }
    __syncthreads();
#pragma unroll
    for (int q = 0; q < 2; q++){
        const int i = (q << 9) + tid;
        const int idx = sidx[i];
        fps_idx[b * NPOINT + i] = idx;
        const float4 c4 = sxyz4[idx];
        float* oxp = out_xyz + b * 3 * NPOINT;
        oxp[i]            = c4.x;
        oxp[NPOINT + i]   = c4.y;
        oxp[2*NPOINT + i] = c4.z;
    }
}

// ---------- 2) ball query: one wave per (b,s), EXACT arithmetic ----------
__global__ __launch_bounds__(256) void ballquery_kernel(const float* __restrict__ xyz,
                                                        const int* __restrict__ fps_idx, int* __restrict__ gidx){
    const int w = (blockIdx.x << 2) + (threadIdx.x >> 6);
    const int lane = threadIdx.x & 63;
    const int b = w >> 10, s = w & 1023;
    const float* px = xyz + (size_t)b * 3 * NPTS;
    const int ci = fps_idx[b * NPOINT + s];
    const float cx = px[ci], cy = px[NPTS+ci], cz = px[2*NPTS+ci];
    int* gout = gidx + (size_t)b * LCOLS + s * NSAMP;
    int have = 0, first_p = 0; bool got = false;
    for (int c0 = 0; c0 < NPTS; c0 += 64){
        int p = c0 + lane;
        float dx = sub_rn(px[p], cx), dy = sub_rn(px[NPTS+p], cy), dz = sub_rn(px[2*NPTS+p], cz);
        float d2 = add_rn(add_rn(mul_rn(dx,dx), mul_rn(dy,dy)), mul_rn(dz,dz));
        bool in = (d2 <= 0.01f);
        unsigned long long m = __ballot(in);
        if (m && !got){ first_p = c0 + __ffsll(m) - 1; got = true; }
        if (in){
            int pos = have + __popcll(m & ((1ull << lane) - 1ull));
            if (pos < NSAMP) gout[pos] = p;
        }
        have += __popcll(m);
        if (have >= NSAMP) break;
    }
    for (int pos = have + lane; pos < NSAMP; pos += 64) gout[pos] = first_p;
}

// ---------- 3) scalar conv+stats for layer0 (gather input; no input activation) ----------
__global__ __launch_bounds__(256) void mm0_kernel(
        const float* __restrict__ xyz, const float* __restrict__ nx,
        const uint16_t* __restrict__ ptsT, const int* __restrict__ gidx,
        const float* __restrict__ wt, const float* __restrict__ bias,
        uint16_t* __restrict__ xout, float* __restrict__ ssc){
    __shared__ __align__(16) float sw[67 * 64];
    __shared__ float sb[64];
    __shared__ __align__(16) float sred[16 * 260];
    const int tid = threadIdx.x;
    for (int i = tid; i < 67 * 64; i += 256) sw[i] = wt[i];
    if (tid < 64) sb[tid] = bias[tid];
    __syncthreads();
    const int b = blockIdx.x >> 7;
    const int ls = ((blockIdx.x & 127) << 8) + tid;
    float f[67];
    {
        const int s = ls >> 5;
        const int g = gidx[(size_t)b * LCOLS + ls];
        const float* px = xyz + (size_t)b * 3 * NPTS;
        const float cx = nx[b*3*NPOINT + s], cy = nx[b*3*NPOINT + NPOINT + s], cz = nx[b*3*NPOINT + 2*NPOINT + s];
        f[0] = sub_rn(px[g], cx); f[1] = sub_rn(px[NPTS+g], cy); f[2] = sub_rn(px[2*NPTS+g], cz);
        const u16x8* pr = (const u16x8*)(ptsT + ((size_t)b * NPTS + (size_t)g) * 64);
#pragma unroll
        for (int jj = 0; jj < 8; jj++){
            u16x8 v = pr[jj];
#pragma unroll
            for (int e = 0; e < 8; e++) f[3 + jj*8 + e] = bf2f(v[e]);
        }
    }
    uint16_t* op = xout + (size_t)b * 64 * LCOLS + ls;
    float* sbck = ssc + (blockIdx.x & (NBUCK-1)) * 256;
    for (int o0 = 0; o0 < 64; o0 += 16){
        float acc[16];
#pragma unroll
        for (int j = 0; j < 16; j++) acc[j] = sb[o0 + j];
#pragma unroll
        for (int c = 0; c < 67; c++){
            const float4* wr = (const float4*)(sw + c * 64 + o0);
            float4 w0_ = wr[0], w1_ = wr[1], w2_ = wr[2], w3_ = wr[3];
            const float fc = f[c];
            acc[0]  = fmaf(w0_.x, fc, acc[0]);  acc[1]  = fmaf(w0_.y, fc, acc[1]);
            acc[2]  = fmaf(w0_.z, fc, acc[2]);  acc[3]  = fmaf(w0_.w, fc, acc[3]);
            acc[4]  = fmaf(w1_.x, fc, acc[4]);  acc[5]  = fmaf(w1_.y, fc, acc[5]);
            acc[6]  = fmaf(w1_.z, fc, acc[6]);  acc[7]  = fmaf(w1_.w, fc, acc[7]);
            acc[8]  = fmaf(w2_.x, fc, acc[8]);  acc[9]  = fmaf(w2_.y, fc, acc[9]);
            acc[10] = fmaf(w2_.z, fc, acc[10]); acc[11] = fmaf(w2_.w, fc, acc[11]);
            acc[12] = fmaf(w3_.x, fc, acc[12]); acc[13] = fmaf(w3_.y, fc, acc[13]);
            acc[14] = fmaf(w3_.z, fc, acc[14]); acc[15] = fmaf(w3_.w, fc, acc[15]);
        }
#pragma unroll
        for (int j = 0; j < 16; j++) op[(size_t)(o0 + j) * LCOLS] = f2bf(acc[j]);
        __syncthreads();
#pragma unroll
        for (int k = 0; k < 16; k++) sred[k * 260 + tid] = acc[k];
        __syncthreads();
        const int ch = tid >> 4, seg = tid & 15;
        float s = 0.f, ss = 0.f;
        const float4* rp = (const float4*)(sred + ch * 260 + seg * 16);
#pragma unroll
        for (int e = 0; e < 4; e++){
            float4 v = rp[e];
            s += v.x + v.y + v.z + v.w;
            ss = fmaf(v.x, v.x, ss); ss = fmaf(v.y, v.y, ss);
            ss = fmaf(v.z, v.z, ss); ss = fmaf(v.w, v.w, ss);
        }
#pragma unroll
        for (int off = 1; off < 16; off <<= 1){
            s += __shfl_xor(s, off); ss += __shfl_xor(ss, off);
        }
        if (seg == 0){
            atomicAdd(&sbck[o0 + ch], s);
            atomicAdd(&sbck[128 + o0 + ch], ss);
        }
    }
}

// ---------- 4) MFMA conv+stats for layers 1/2 (CIN=64) ----------
// Input: xin bf16 [64][LCOLS] (raw prev conv out) ; apply prev-BN affine + relu during staging.
// A = Wpack bf16 [kc][COUT][e] ; B staged [kc][256][e]. D[m=o][n=col].
template<int COUT, bool WRITE, bool MAXMIN>
__global__ __launch_bounds__(256) void mfma_mm_kernel(
        const uint16_t* __restrict__ xin, const uint16_t* __restrict__ wpack,
        const float* __restrict__ bias,
        const float* __restrict__ pssc, const float* __restrict__ pg, const float* __restrict__ pbeta,
        uint16_t* __restrict__ xout, float* __restrict__ ssc,
        unsigned* __restrict__ mmax, unsigned* __restrict__ mmin){
    constexpr int MT = COUT / 16;
    __shared__ __align__(16) uint16_t sB[8 * 256 * 8];       // 32KB
    __shared__ __align__(16) uint16_t sA[8 * COUT * 8];      // 8/16KB
    __shared__ float sa_[64], sc_[64], sb_[COUT];
    __shared__ float sred_s[4][COUT], sred_ss[4][COUT];
    __shared__ float sred_mx[MAXMIN ? 4 : 1][COUT], sred_mn[MAXMIN ? 4 : 1][COUT];
    const int tid = threadIdx.x;
    const int b = blockIdx.x >> 7;
    const int n0 = (blockIdx.x & 127) << 8;

    if (tid < 64){
        float s = 0.f, ss = 0.f;
#pragma unroll 4
        for (int k = 0; k < NBUCK; k++){ s += pssc[k*256 + tid]; ss += pssc[k*256 + 128 + tid]; }
        const float inv = 1.0f / NTOT;
        float mean = s * inv;
        float var  = ss * inv - mean * mean;
        float a = pg[tid] / sqrtf(var + 1e-5f);
        sa_[tid] = a;
        sc_[tid] = fmaf(-mean, a, pbeta[tid]);
    }
    if (tid < COUT) sb_[tid] = bias[tid];
    for (int i = tid; i < COUT * 64; i += 256) sA[i] = wpack[i];
    __syncthreads();

    // stage B: thread = column
    {
        const uint16_t* xp = xin + (size_t)b * 64 * LCOLS + (n0 + tid);
#pragma unroll 8
        for (int c = 0; c < 64; c++){
            float v = bf2f(xp[(size_t)c * LCOLS]);
            v = fmaxf(fmaf(sa_[c], v, sc_[c]), 0.0f);
            sB[((c >> 3) * 256 + tid) * 8 + (c & 7)] = f2bf(v);
        }
    }
    __syncthreads();

    const int lane = tid & 63, w = tid >> 6;
    const int lhi = lane >> 4, llo = lane & 15;
    fx4 acc[MT][4];
#pragma unroll
    for (int mt = 0; mt < MT; mt++)
#pragma unroll
        for (int nt = 0; nt < 4; nt++) acc[mt][nt] = fx4{0.f, 0.f, 0.f, 0.f};

#pragma unroll
    for (int kk = 0; kk < 2; kk++){
        bf16x8 bfrag[4];
#pragma unroll
        for (int nt = 0; nt < 4; nt++){
            int n = w * 64 + nt * 16 + llo;
            bfrag[nt] = *(const bf16x8*)&sB[((kk*4 + lhi) * 256 + n) * 8];
        }
#pragma unroll
        for (int mt = 0; mt < MT; mt++){
            bf16x8 afrag = *(const bf16x8*)&sA[((kk*4 + lhi) * COUT + mt*16 + llo) * 8];
#pragma unroll
            for (int nt = 0; nt < 4; nt++)
                acc[mt][nt] = __builtin_amdgcn_mfma_f32_16x16x32_bf16(afrag, bfrag[nt], acc[mt][nt], 0, 0, 0);
        }
    }

    // bias add ; optional write ; per-wave stats
#pragma unroll
    for (int mt = 0; mt < MT; mt++){
#pragma unroll
        for (int j = 0; j < 4; j++){
            const int ch = mt*16 + lhi*4 + j;
            const float bv = sb_[ch];
            float a0 = acc[mt][0][j] + bv, a1 = acc[mt][1][j] + bv;
            float a2 = acc[mt][2][j] + bv, a3 = acc[mt][3][j] + bv;
            acc[mt][0][j] = a0; acc[mt][1][j] = a1; acc[mt][2][j] = a2; acc[mt][3][j] = a3;
            if constexpr (WRITE){
                uint16_t* op = xout + (size_t)b * COUT * LCOLS + (size_t)ch * LCOLS + n0 + w*64 + llo;
                op[0]  = f2bf(a0); op[16] = f2bf(a1); op[32] = f2bf(a2); op[48] = f2bf(a3);
            }
            float s  = (a0 + a1) + (a2 + a3);
            float ss = fmaf(a0, a0, fmaf(a1, a1, fmaf(a2, a2, a3*a3)));
            float mx = 0.f, mn = 0.f;
            if constexpr (MAXMIN){
                mx = fmaxf(fmaxf(a0, a1), fmaxf(a2, a3));
                mn = fminf(fminf(a0, a1), fminf(a2, a3));
            }
#pragma unroll
            for (int off = 1; off < 16; off <<= 1){
                s += __shfl_xor(s, off); ss += __shfl_xor(ss, off);
                if constexpr (MAXMIN){ mx = fmaxf(mx, __shfl_xor(mx, off)); mn = fminf(mn, __shfl_xor(mn, off)); }
            }
            if (llo == 0){
                sred_s[w][ch] = s; sred_ss[w][ch] = ss;
                if constexpr (MAXMIN){ sred_mx[w][ch] = mx; sred_mn[w][ch] = mn; }
            }
        }
    }
    __syncthreads();
    if (tid < COUT){
        float s  = sred_s[0][tid]  + sred_s[1][tid]  + sred_s[2][tid]  + sred_s[3][tid];
        float ss = sred_ss[0][tid] + sred_ss[1][tid] + sred_ss[2][tid] + sred_ss[3][tid];
        float* sbck = ssc + (blockIdx.x & (NBUCK-1)) * 256;
        atomicAdd(&sbck[tid], s);
        atomicAdd(&sbck[128 + tid], ss);
        if constexpr (MAXMIN){
            float mx = fmaxf(fmaxf(sred_mx[0][tid], sred_mx[1][tid]), fmaxf(sred_mx[2][tid], sred_mx[3][tid]));
            float mn = fminf(fminf(sred_mn[0][tid], sred_mn[1][tid]), fminf(sred_mn[2][tid], sred_mn[3][tid]));
            atomicMax(&mmax[b * 128 + tid], fkey(mx));
            atomicMin(&mmin[b * 128 + tid], fkey(mn));
        }
    }
}

// ---------- 5) finalize: out = relu(a * (a>=0 ? max : min) + c) per (b,ch) ----------
__global__ __launch_bounds__(64) void final_kernel(const float* __restrict__ ssc, const float* __restrict__ g2,
                                                   const float* __restrict__ be2, const unsigned* __restrict__ mmax,
                                                   const unsigned* __restrict__ mmin, float* __restrict__ out){
    const int t = blockIdx.x * 64 + threadIdx.x;   // 0..2047 : b*128+o
    const int o = t & 127;
    float s = 0.f, ss = 0.f;
    for (int k = 0; k < NBUCK; k++){ s += ssc[k*256 + o]; ss += ssc[k*256 + 128 + o]; }
    const float inv = 1.0f / NTOT;
    float mean = s * inv;
    float var  = ss * inv - mean * mean;
    float a = g2[o] / sqrtf(var + 1e-5f);
    float c = fmaf(-mean, a, be2[o]);
    unsigned k = (a >= 0.f) ? mmax[t] : mmin[t];
    float x = funkey(k);
    out[49152 + t] = fmaxf(fmaf(a, x, c), 0.0f);
}

extern "C" void kernel_launch(void* const* d_in, const int* in_sizes, int n_in,
                              void* d_out, int out_size, void* d_ws, size_t ws_size,
                              hipStream_t stream){
    const float* xyz = (const float*)d_in[0];
    const float* pts = (const float*)d_in[1];
    const float* w0  = (const float*)d_in[2];  const float* b0  = (const float*)d_in[3];
    const float* g0  = (const float*)d_in[4];  const float* be0 = (const float*)d_in[5];
    const float* w1  = (const float*)d_in[6];  const float* b1  = (const float*)d_in[7];
    const float* g1  = (const float*)d_in[8];  const float* be1 = (const float*)d_in[9];
    const float* w2  = (const float*)d_in[10]; const float* b2  = (const float*)d_in[11];
    const float* g2  = (const float*)d_in[12]; const float* be2 = (const float*)d_in[13];
    float* out = (float*)d_out;
    char* ws = (char*)d_ws;

    int*      fps_idx = (int*)(ws + OFF_FPS);
    int*      gidx    = (int*)(ws + OFF_GIDX);
    float*    ssc0    = (float*)(ws + OFF_SSC);
    float*    ssc1    = ssc0 + NBUCK*256;
    float*    ssc2    = ssc1 + NBUCK*256;
    unsigned* mmax    = (unsigned*)(ws + OFF_MM);
    unsigned* mmin    = mmax + 2048;
    float*    wt0     = (float*)(ws + OFF_WT);
    uint16_t* wpk1    = (uint16_t*)(ws + OFF_WPK1);
    uint16_t* wpk2    = (uint16_t*)(ws + OFF_WPK2);
    uint16_t* t0      = (uint16_t*)(ws + OFF_T0);
    uint16_t* t1      = (uint16_t*)(ws + OFF_T1);
    uint16_t* ptsT    = (uint16_t*)(ws + OFF_PTST);

    hipMemsetAsync(ws + OFF_SSC, 0, 3 * NBUCK * 256 * 4, stream);
    hipMemsetAsync(ws + OFF_MM, 0x00, 8192, stream);
    hipMemsetAsync(ws + OFF_MM + 8192, 0xFF, 8192, stream);

    fps_fused_kernel<<<2080, 512, 0, stream>>>(xyz, fps_idx, out, pts, ptsT,
                                               w0, w1, w2, wt0, wpk1, wpk2);
    ballquery_kernel<<<4096, 256, 0, stream>>>(xyz, fps_idx, gidx);

    mm0_kernel<<<2048, 256, 0, stream>>>(xyz, out, ptsT, gidx, wt0, b0, t0, ssc0);

    mfma_mm_kernel<64, true, false><<<2048, 256, 0, stream>>>(
        t0, wpk1, b1, ssc0, g0, be0, t1, ssc1, nullptr, nullptr);

    mfma_mm_kernel<128, false, true><<<2048, 256, 0, stream>>>(
        t1, wpk2, b2, ssc1, g1, be1, nullptr, ssc2, mmax, mmin);

    final_kernel<<<32, 64, 0, stream>>>(ssc2, g2, be2, mmax, mmin, out);
}